// Round 1
// baseline (1658.786 us; speedup 1.0000x reference)
//
#include <hip/hip_runtime.h>
#include <hip/hip_bf16.h>
#include <cstdint>

// ---------------------------------------------------------------------------
// Types / helpers
// ---------------------------------------------------------------------------
typedef __bf16 bf16_t;
typedef __attribute__((ext_vector_type(8))) __bf16 bf16x8;
typedef __attribute__((ext_vector_type(4))) float f32x4;

__device__ __forceinline__ float b2f(ushort u) {
    union { float f; uint32_t i; } x; x.i = ((uint32_t)u) << 16; return x.f;
}
__device__ __forceinline__ ushort f2b(float f) {
    uint32_t i = __builtin_bit_cast(uint32_t, f);
    uint32_t r = (i + 0x7FFFu + ((i >> 16) & 1u)) >> 16;   // RNE
    return (ushort)r;
}

// async global->LDS, 16 bytes per lane; lds ptr must be wave-uniform base
__device__ __forceinline__ void g2l16(const ushort* gp, ushort* lp) {
    __builtin_amdgcn_global_load_lds(
        (const __attribute__((address_space(1))) uint32_t*)gp,
        (__attribute__((address_space(3))) uint32_t*)lp, 16, 0, 0);
}

// ---------------------------------------------------------------------------
// LN1 + pack x into GEMM-A layout: A1[patch=(b*32+gh)*32+gw][(i*8+j)*32+c] bf16
// ---------------------------------------------------------------------------
__global__ __launch_bounds__(256) void ln1_pack(
    const float* __restrict__ x, const float* __restrict__ g,
    const float* __restrict__ b, ushort* __restrict__ A1) {
    int pix = blockIdx.x * 256 + threadIdx.x;      // 0..131071
    const float4* xp = (const float4*)(x + (size_t)pix * 32);
    float v[32]; float s = 0.f;
#pragma unroll
    for (int i = 0; i < 8; ++i) {
        float4 f = xp[i];
        v[i*4+0] = f.x; v[i*4+1] = f.y; v[i*4+2] = f.z; v[i*4+3] = f.w;
        s += f.x + f.y + f.z + f.w;
    }
    float mu = s * (1.f/32.f), s2 = 0.f;
#pragma unroll
    for (int i = 0; i < 32; ++i) { float d = v[i]-mu; s2 += d*d; }
    float inv = rsqrtf(s2 * (1.f/32.f) + 1e-6f);
    int w = pix & 255, h = (pix >> 8) & 255, bb = pix >> 16;
    size_t row = ((size_t)bb*32 + (h>>3))*32 + (w>>3);
    ushort* dst = A1 + row*2048 + (size_t)((h&7)*8 + (w&7))*32;
    ushort o[32];
#pragma unroll
    for (int i = 0; i < 32; ++i) o[i] = f2b((v[i]-mu)*inv*g[i] + b[i]);
    uint4* d4 = (uint4*)dst; const uint4* s4 = (const uint4*)o;
#pragma unroll
    for (int i = 0; i < 4; ++i) d4[i] = s4[i];
}

// ---------------------------------------------------------------------------
// Weight fp32 [K,N] (n-contig) -> bf16 [N,K] (k-contig) transpose+convert
// ---------------------------------------------------------------------------
__global__ __launch_bounds__(256) void wcvt(
    const float* __restrict__ W, ushort* __restrict__ WT, int K, int N) {
    __shared__ float tile[64][65];
    int n0 = blockIdx.x * 64, k0 = blockIdx.y * 64;
    int t = threadIdx.x;
    int col4 = (t & 15) * 4, krow = t >> 4;
#pragma unroll
    for (int it = 0; it < 4; ++it) {
        int kk = it*16 + krow;
        float4 f = *(const float4*)(W + (size_t)(k0+kk)*N + n0 + col4);
        tile[kk][col4+0] = f.x; tile[kk][col4+1] = f.y;
        tile[kk][col4+2] = f.z; tile[kk][col4+3] = f.w;
    }
    __syncthreads();
    int n = t >> 2, ch = t & 3;
    ushort o[16];
#pragma unroll
    for (int i = 0; i < 16; ++i) o[i] = f2b(tile[ch*16 + i][n]);
    uint4* dst = (uint4*)(WT + (size_t)(n0+n)*K + k0 + ch*16);
    dst[0] = ((const uint4*)o)[0];
    dst[1] = ((const uint4*)o)[1];
}

// ---------------------------------------------------------------------------
// 256x256 bf16 MFMA GEMM, BK=32, 8 waves (2M x 4N), 128x64 C per wave.
// 4-deep LDS ring (128 KiB), staging issued 3 tiles ahead, counted vmcnt(8)
// at a single raw s_barrier per K-step (loads stay in flight across the
// barrier -- T3/T4). Slot-major LDS layout [slot][256 rows][8 elems]:
//   - global_load_lds (linear dest) fills 64 consecutive rows of one slot
//   - fragment ds_read_b128: 16 lanes stride 16B -> 2-way bank alias (free)
// T5 setprio around MFMA cluster; T1 bijective XCD swizzle (grid % 8 == 0).
// EPI=0: C = acc + bias[n] -> bf16 Cb (per-wave LDS arena transpose + uint4)
// EPI=1: fp32 split-K partials -> Out + z*M*N
// Hazard notes:
//   - buffer reuse distance 4: STAGE(ti+3) targets buf read at iter ti-1,
//     issued after that iter's barrier -> no WAR.
//   - per-wave vmcnt counts only own loads; the barrier (all waves waited
//     their own counted vmcnt first) publishes cross-wave staging.
//   - waits + s_barrier in ONE volatile asm with memory clobber so no LDS
//     read/stage can be scheduled across it.
//   - tail: vmcnt 8 -> 4 -> 0 as staging stops; M == 2048 assumed (mi=swz&7).
// ---------------------------------------------------------------------------
template <int EPI>
__global__ __launch_bounds__(512, 2) void gemm256(
    const ushort* __restrict__ A, const ushort* __restrict__ Bt,
    const float* __restrict__ bias, ushort* __restrict__ Cb,
    float* __restrict__ Out, int M, int N, int K, int KS) {
    __shared__ __align__(16) ushort sA[32768];   // 4 bufs x [4 slots][256][8]
    __shared__ __align__(16) ushort sB[32768];   // 64 KiB each, 128 KiB total
    const int tid  = threadIdx.x;
    const int wave = tid >> 6, lane = tid & 63;
    const int lrow = lane & 15, lquad = lane >> 4;
    const int wm = wave >> 2, wn = wave & 3;

    // XCD-aware bijective block swizzle (gridDim.x % 8 == 0 for all uses)
    const int nwg  = gridDim.x;
    const int flat = blockIdx.x;
    const int swz  = (flat & 7) * (nwg >> 3) + (flat >> 3);
    const int m0 = (swz & 7) * 256;              // M/256 == 8 always here
    const int n0 = (swz >> 3) * 256;

    const int kb  = (EPI == 1) ? blockIdx.z * KS : 0;
    const int NTl = KS >> 5;                     // K-tiles of 32

    // staging: 16 segments (slot, rowgroup) per matrix; 2 per wave.
    // wave-issue fills 64 consecutive rows of one slot (1 KiB linear LDS).
    const int seg0 = wave * 2, seg1 = seg0 + 1;
    const ushort* aS0 = A  + (size_t)(m0 + (seg0 >> 2)*64 + lane)*K + kb + (seg0 & 3)*8;
    const ushort* aS1 = A  + (size_t)(m0 + (seg1 >> 2)*64 + lane)*K + kb + (seg1 & 3)*8;
    const ushort* bS0 = Bt + (size_t)(n0 + (seg0 >> 2)*64 + lane)*K + kb + (seg0 & 3)*8;
    const ushort* bS1 = Bt + (size_t)(n0 + (seg1 >> 2)*64 + lane)*K + kb + (seg1 & 3)*8;
    ushort* aD0 = sA + (seg0 & 3)*2048 + (seg0 >> 2)*512;
    ushort* aD1 = sA + (seg1 & 3)*2048 + (seg1 >> 2)*512;
    ushort* bD0 = sB + (seg0 & 3)*2048 + (seg0 >> 2)*512;
    ushort* bD1 = sB + (seg1 & 3)*2048 + (seg1 >> 2)*512;

    // fragment read bases: lane l -> row (l&15), k-slot (l>>4)
    const ushort* pA = sA + lquad*2048 + (wm*128 + lrow)*8;
    const ushort* pB = sB + lquad*2048 + (wn*64  + lrow)*8;

    f32x4 acc[8][4];
#pragma unroll
    for (int i = 0; i < 8; ++i)
#pragma unroll
        for (int j = 0; j < 4; ++j) acc[i][j] = f32x4{0.f, 0.f, 0.f, 0.f};

#define STAGE(TI) { const int _b = (TI) & 3; const size_t _ko = (size_t)(TI) * 32; \
    g2l16(aS0 + _ko, aD0 + _b*8192); g2l16(aS1 + _ko, aD1 + _b*8192);              \
    g2l16(bS0 + _ko, bD0 + _b*8192); g2l16(bS1 + _ko, bD1 + _b*8192); }

    // prologue: tiles 0,1,2 in flight; drain tile 0, keep 8 loads flying
    STAGE(0); STAGE(1); STAGE(2);
    asm volatile("s_waitcnt vmcnt(8)\n\ts_barrier" ::: "memory");

    for (int ti = 0; ti < NTl; ++ti) {
        if (ti + 3 < NTl) STAGE(ti + 3);
        const ushort* bufA = pA + (ti & 3) * 8192;
        const ushort* bufB = pB + (ti & 3) * 8192;
        bf16x8 af[8], bg[4];
#pragma unroll
        for (int i = 0; i < 8; ++i)
            af[i] = __builtin_bit_cast(bf16x8, *(const uint4*)(bufA + i*128));
#pragma unroll
        for (int j = 0; j < 4; ++j)
            bg[j] = __builtin_bit_cast(bf16x8, *(const uint4*)(bufB + j*128));
        __builtin_amdgcn_s_setprio(1);
#pragma unroll
        for (int i = 0; i < 8; ++i)
#pragma unroll
            for (int j = 0; j < 4; ++j)
                acc[i][j] = __builtin_amdgcn_mfma_f32_16x16x32_bf16(
                    af[i], bg[j], acc[i][j], 0, 0, 0);
        __builtin_amdgcn_s_setprio(0);
        // single barrier per K-step; counted vmcnt keeps 2 tiles in flight
        if (ti + 3 < NTl)      asm volatile("s_waitcnt vmcnt(8)\n\ts_barrier" ::: "memory");
        else if (ti + 2 < NTl) asm volatile("s_waitcnt vmcnt(4)\n\ts_barrier" ::: "memory");
        else if (ti + 1 < NTl) asm volatile("s_waitcnt vmcnt(0)\n\ts_barrier" ::: "memory");
        // ti == NTl-1: nothing outstanding; epilogue has its own sync
    }
#undef STAGE

    if constexpr (EPI == 0) {
        float bvj[4];
#pragma unroll
        for (int j = 0; j < 4; ++j) bvj[j] = bias[n0 + wn*64 + j*16 + lrow];
        __syncthreads();                    // all waves done with sA/sB
        ushort* warena = sA + wave * 2048;  // 4 KB per wave: 32 rows x 64 cols
#pragma unroll
        for (int pass = 0; pass < 4; ++pass) {
#pragma unroll
            for (int ih = 0; ih < 2; ++ih) {
                const int i = pass*2 + ih;
#pragma unroll
                for (int j = 0; j < 4; ++j)
#pragma unroll
                    for (int re = 0; re < 4; ++re) {
                        int mrow = ih*16 + lquad*4 + re;     // 0..31
                        int col  = j*16 + lrow;              // 0..63
                        warena[mrow*64 + col] = f2b(acc[i][j][re] + bvj[j]);
                    }
            }
            // intra-wave only (lockstep) -> no barrier needed
#pragma unroll
            for (int t2 = 0; t2 < 4; ++t2) {
                int chunk = t2*64 + lane;          // 0..255
                int row = chunk >> 3, seg = chunk & 7;
                uint4 v = *(const uint4*)&warena[row*64 + seg*8];
                *(uint4*)&Cb[(size_t)(m0 + wm*128 + pass*32 + row)*N
                             + n0 + wn*64 + seg*8] = v;
            }
        }
    } else {
        float* P = Out + (size_t)blockIdx.z * M * N;
#pragma unroll
        for (int j = 0; j < 4; ++j) {
            int n = n0 + wn*64 + j*16 + lrow;
#pragma unroll
            for (int i = 0; i < 8; ++i) {
                int mbase = m0 + wm*128 + i*16 + lquad*4;
#pragma unroll
                for (int re = 0; re < 4; ++re)
                    P[(size_t)(mbase + re)*N + n] = acc[i][j][re];
            }
        }
    }
}

// ---------------------------------------------------------------------------
// Per-patch: 8x8 circular conv (q ⊛ k), LN2 over c, gate by v, pack A2 rows.
// One block per patch; thread t -> (head = t>>5, c = t&31). A2 aliases Qb
// (each row fully consumed into regs before overwrite).
// ---------------------------------------------------------------------------
__global__ __launch_bounds__(256, 3) void conv_gate(
    const ushort* __restrict__ Qb, const ushort* __restrict__ Kb,
    const ushort* __restrict__ Vb, const float* __restrict__ ln2_s,
    const float* __restrict__ ln2_b, ushort* __restrict__ A2) {
    __shared__ ushort sT[64 * 258];                // 33 KB, [p or a][h*32+c]
    const int t = threadIdx.x;
    const int m = blockIdx.x;
    const int c = t & 31, h = t >> 5;
    const ushort* Qrow = Qb + (size_t)m * 16384;
    const ushort* Krow = Kb + (size_t)m * 16384;
    const ushort* Vrow = Vb + (size_t)m * 16384;

    // stage transposed: global f = cc*512 + p*8 + head  ->  sT[p*258+head*32+cc]
#define STAGE_T(SRC)                                                        \
    {                                                                       \
        _Pragma("unroll")                                                   \
        for (int it = 0; it < 8; ++it) {                                    \
            int ci = it*256 + t;                                            \
            int p = ci & 63, cc = ci >> 6;                                  \
            uint4 w = ((const uint4*)(SRC))[ci];                            \
            uint uu[4] = {w.x, w.y, w.z, w.w};                              \
            _Pragma("unroll")                                               \
            for (int e = 0; e < 4; ++e) {                                   \
                sT[p*258 + (2*e  )*32 + cc] = (ushort)(uu[e] & 0xffffu);    \
                sT[p*258 + (2*e+1)*32 + cc] = (ushort)(uu[e] >> 16);        \
            }                                                               \
        }                                                                   \
    }

    float q[64];
    STAGE_T(Qrow);
    __syncthreads();
#pragma unroll
    for (int p = 0; p < 64; ++p) q[p] = b2f(sT[p*258 + t]);
    __syncthreads();
    STAGE_T(Krow);     // K stays in LDS for the conv loop
    __syncthreads();
#undef STAGE_T

    const float scl = ln2_s[c], bia = ln2_b[c];
    ushort* A2row = A2 + (size_t)m * 16384;
    const ushort* vbase = Vrow + c*512 + h;        // + p0*64 + p1*8

#pragma unroll
    for (int p0 = 0; p0 < 8; ++p0) {
        // prefetch V octet (consumed after the FMA nest -> latency hidden)
        ushort vraw[8];
#pragma unroll
        for (int p1 = 0; p1 < 8; ++p1) vraw[p1] = vbase[p0*64 + p1*8];

        float o[8];
#pragma unroll
        for (int p1 = 0; p1 < 8; ++p1) o[p1] = 0.f;
#pragma unroll
        for (int b0 = 0; b0 < 8; ++b0) {
            const int qr = ((p0 - b0) & 7) * 8;
#pragma unroll
            for (int b1 = 0; b1 < 8; ++b1) {
                float kv = b2f(sT[(b0*8 + b1)*258 + t]);
#pragma unroll
                for (int p1 = 0; p1 < 8; ++p1)
                    o[p1] += kv * q[qr + ((p1 - b1) & 7)];
            }
        }

        // batched LN2 butterfly over the 32 channels (lanes grouped by 32)
        float s1[8], s2[8];
#pragma unroll
        for (int p1 = 0; p1 < 8; ++p1) { s1[p1] = o[p1]; s2[p1] = o[p1]*o[p1]; }
#pragma unroll
        for (int mask = 1; mask <= 16; mask <<= 1) {
#pragma unroll
            for (int p1 = 0; p1 < 8; ++p1) {
                s1[p1] += __shfl_xor(s1[p1], mask, 64);
                s2[p1] += __shfl_xor(s2[p1], mask, 64);
            }
        }
#pragma unroll
        for (int p1 = 0; p1 < 8; ++p1) {
            float mu  = s1[p1] * 0.03125f;
            float var = s2[p1] * 0.03125f - mu * mu;
            float inv = rsqrtf(var + 1e-6f);
            float on  = (o[p1] - mu) * inv * scl + bia;
            A2row[(p0*8 + p1)*256 + t] = f2b(b2f(vraw[p1]) * on);
        }
    }
}

// ---------------------------------------------------------------------------
// reduce_out: out[pix] = x[pix] + bo[n] + sum_z P[z][m][n], patch->pixel remap
// ---------------------------------------------------------------------------
__global__ __launch_bounds__(256) void reduce_out(
    const float* __restrict__ Pp, const float* __restrict__ x,
    const float* __restrict__ bo, float* __restrict__ out) {
    __shared__ float sn[32*65];                    // padded [c][64]
    const int t = threadIdx.x, m = blockIdx.x;
    float4 s0 = {0.f,0.f,0.f,0.f}, s1 = {0.f,0.f,0.f,0.f};
#pragma unroll
    for (int z = 0; z < 4; ++z) {
        const float4* base =
            (const float4*)(Pp + ((size_t)z*2048 + m) * 2048);
        float4 u = base[t], v = base[256 + t];
        s0.x += u.x; s0.y += u.y; s0.z += u.z; s0.w += u.w;
        s1.x += v.x; s1.y += v.y; s1.z += v.z; s1.w += v.w;
    }
    {
        int na = t*4;                              // chunk t   -> n = 4t
        int nb = (256 + t)*4;                      // chunk 256+t
        float va[4] = {s0.x, s0.y, s0.z, s0.w};
        float vb[4] = {s1.x, s1.y, s1.z, s1.w};
#pragma unroll
        for (int e = 0; e < 4; ++e) {
            int n1 = na + e, n2 = nb + e;
            sn[(n1 >> 6)*65 + (n1 & 63)] = va[e];
            sn[(n2 >> 6)*65 + (n2 & 63)] = vb[e];
        }
    }
    __syncthreads();
    const int c = t & 31, pi = t >> 5;
    const int bb = m >> 10, gh = (m >> 5) & 31, gw = m & 31;
#pragma unroll
    for (int it = 0; it < 8; ++it) {
        int p = it*8 + pi;                         // 0..63
        int p0 = p >> 3, p1 = p & 7;
        int n = c*64 + p;
        size_t oi = ((size_t)((bb*256 + gh*8 + p0)*256 + gw*8 + p1))*32 + c;
        out[oi] = x[oi] + bo[n] + sn[c*65 + p];
    }
}

// ---------------------------------------------------------------------------
extern "C" void kernel_launch(void* const* d_in, const int* in_sizes, int n_in,
                              void* d_out, int out_size, void* d_ws, size_t ws_size,
                              hipStream_t stream) {
    (void)in_sizes; (void)n_in; (void)out_size; (void)ws_size;
    const float* x    = (const float*)d_in[0];
    const float* ln1s = (const float*)d_in[1];
    const float* ln1b = (const float*)d_in[2];
    const float* Wq   = (const float*)d_in[3];
    const float* bq   = (const float*)d_in[4];
    const float* Wk   = (const float*)d_in[5];
    const float* bk   = (const float*)d_in[6];
    const float* Wv   = (const float*)d_in[7];
    const float* bv   = (const float*)d_in[8];
    const float* ln2s = (const float*)d_in[9];
    const float* ln2b = (const float*)d_in[10];
    const float* Wo   = (const float*)d_in[11];
    const float* bo   = (const float*)d_in[12];
    float* out = (float*)d_out;

    char* ws = (char*)d_ws;
    ushort* A1 = (ushort*)(ws);                      //  8.0 MB  [2048,2048] bf16
    ushort* WT = (ushort*)(ws + 8388608);            // 64.0 MB  [N,K] bf16
    ushort* Qb = (ushort*)(ws + 75497472);           // 64.0 MB  [2048,16384] bf16
    ushort* Kb = (ushort*)(ws + 142606336);          // 64.0 MB
    ushort* Vb = (ushort*)(ws + 209715200);          // 64.0 MB  (end 276.8 MB)
    ushort* A2 = Qb;                                 // aliases Qb (safe: per-row)
    float*  Pp = (float*)Kb;                         // 64.0 MB split-K partials
                                                     // (Kb dead after conv_gate)

    ln1_pack<<<512, 256, 0, stream>>>(x, ln1s, ln1b, A1);

    wcvt<<<dim3(256, 32), 256, 0, stream>>>(Wq, WT, 2048, 16384);
    gemm256<0><<<dim3(512, 1, 1), 512, 0, stream>>>(A1, WT, bq, Qb, nullptr,
                                                    2048, 16384, 2048, 2048);
    wcvt<<<dim3(256, 32), 256, 0, stream>>>(Wk, WT, 2048, 16384);
    gemm256<0><<<dim3(512, 1, 1), 512, 0, stream>>>(A1, WT, bk, Kb, nullptr,
                                                    2048, 16384, 2048, 2048);
    wcvt<<<dim3(256, 32), 256, 0, stream>>>(Wv, WT, 2048, 16384);
    gemm256<0><<<dim3(512, 1, 1), 512, 0, stream>>>(A1, WT, bv, Vb, nullptr,
                                                    2048, 16384, 2048, 2048);

    conv_gate<<<2048, 256, 0, stream>>>(Qb, Kb, Vb, ln2s, ln2b, A2);

    wcvt<<<dim3(32, 256), 256, 0, stream>>>(Wo, WT, 16384, 2048);
    gemm256<1><<<dim3(64, 1, 4), 512, 0, stream>>>(A2, WT, nullptr, nullptr, Pp,
                                                   2048, 2048, 16384, 4096);
    reduce_out<<<2048, 256, 0, stream>>>(Pp, x, bo, out);
}

// Round 2
// 1349.026 us; speedup vs baseline: 1.2296x; 1.2296x over previous
//
#include <hip/hip_runtime.h>
#include <hip/hip_bf16.h>
#include <cstdint>

// ---------------------------------------------------------------------------
// Types / helpers
// ---------------------------------------------------------------------------
typedef __bf16 bf16_t;
typedef __attribute__((ext_vector_type(8))) __bf16 bf16x8;
typedef __attribute__((ext_vector_type(4))) float f32x4;

__device__ __forceinline__ float b2f(ushort u) {
    union { float f; uint32_t i; } x; x.i = ((uint32_t)u) << 16; return x.f;
}
__device__ __forceinline__ ushort f2b(float f) {
    uint32_t i = __builtin_bit_cast(uint32_t, f);
    uint32_t r = (i + 0x7FFFu + ((i >> 16) & 1u)) >> 16;   // RNE
    return (ushort)r;
}

// async global->LDS, 16 bytes per lane; lds ptr must be wave-uniform base
__device__ __forceinline__ void g2l16(const ushort* gp, ushort* lp) {
    __builtin_amdgcn_global_load_lds(
        (const __attribute__((address_space(1))) uint32_t*)gp,
        (__attribute__((address_space(3))) uint32_t*)lp, 16, 0, 0);
}

// ---------------------------------------------------------------------------
// LN1 + pack x into GEMM-A layout: A1[patch=(b*32+gh)*32+gw][(i*8+j)*32+c] bf16
// ---------------------------------------------------------------------------
__global__ __launch_bounds__(256) void ln1_pack(
    const float* __restrict__ x, const float* __restrict__ g,
    const float* __restrict__ b, ushort* __restrict__ A1) {
    int pix = blockIdx.x * 256 + threadIdx.x;      // 0..131071
    const float4* xp = (const float4*)(x + (size_t)pix * 32);
    float v[32]; float s = 0.f;
#pragma unroll
    for (int i = 0; i < 8; ++i) {
        float4 f = xp[i];
        v[i*4+0] = f.x; v[i*4+1] = f.y; v[i*4+2] = f.z; v[i*4+3] = f.w;
        s += f.x + f.y + f.z + f.w;
    }
    float mu = s * (1.f/32.f), s2 = 0.f;
#pragma unroll
    for (int i = 0; i < 32; ++i) { float d = v[i]-mu; s2 += d*d; }
    float inv = rsqrtf(s2 * (1.f/32.f) + 1e-6f);
    int w = pix & 255, h = (pix >> 8) & 255, bb = pix >> 16;
    size_t row = ((size_t)bb*32 + (h>>3))*32 + (w>>3);
    ushort* dst = A1 + row*2048 + (size_t)((h&7)*8 + (w&7))*32;
    ushort o[32];
#pragma unroll
    for (int i = 0; i < 32; ++i) o[i] = f2b((v[i]-mu)*inv*g[i] + b[i]);
    uint4* d4 = (uint4*)dst; const uint4* s4 = (const uint4*)o;
#pragma unroll
    for (int i = 0; i < 4; ++i) d4[i] = s4[i];
}

// ---------------------------------------------------------------------------
// Weight fp32 [K,N] (n-contig) -> bf16 [N,K] (k-contig) transpose+convert
// ---------------------------------------------------------------------------
__global__ __launch_bounds__(256) void wcvt(
    const float* __restrict__ W, ushort* __restrict__ WT, int K, int N) {
    __shared__ float tile[64][65];
    int n0 = blockIdx.x * 64, k0 = blockIdx.y * 64;
    int t = threadIdx.x;
    int col4 = (t & 15) * 4, krow = t >> 4;
#pragma unroll
    for (int it = 0; it < 4; ++it) {
        int kk = it*16 + krow;
        float4 f = *(const float4*)(W + (size_t)(k0+kk)*N + n0 + col4);
        tile[kk][col4+0] = f.x; tile[kk][col4+1] = f.y;
        tile[kk][col4+2] = f.z; tile[kk][col4+3] = f.w;
    }
    __syncthreads();
    int n = t >> 2, ch = t & 3;
    ushort o[16];
#pragma unroll
    for (int i = 0; i < 16; ++i) o[i] = f2b(tile[ch*16 + i][n]);
    uint4* dst = (uint4*)(WT + (size_t)(n0+n)*K + k0 + ch*16);
    dst[0] = ((const uint4*)o)[0];
    dst[1] = ((const uint4*)o)[1];
}

// ---------------------------------------------------------------------------
// 256x256 bf16 MFMA GEMM, BK=32, 8 waves (2M x 4N), 128x64 C per wave.
// R1 changes vs R0 (R0 verified correct but latency/fetch-bound at 478 TF):
//  1. FINE-GRAINED 2-phase schedule per K-tile (m201/m196 pattern): each
//     phase = {ds_read subtile (8 or 4 x b128) || stage 2 global_load_lds}
//     -> s_barrier -> lgkmcnt(0)+sched_barrier -> setprio(1) 16 MFMA
//     setprio(0) -> s_barrier. Counted vmcnt(8) ONCE per K-tile (never 0
//     in main loop); 3-deep ring identical to R0's verified accounting.
//  2. B-SHARING XCD SWIZZLE: n_tile = (blk>>6)*8 + (blk&7), m_tile =
//     (blk>>3)&7  ->  all 8 m-sharers of a B-panel sit on ONE XCD (blk%8),
//     and only ~4 n-panels are concurrently live per XCD (~4 MB B working
//     set vs 16 MB in R0 which thrashed L2: FETCH 526 MB, 7x ideal).
// Hazards (same ring as R0): STAGE(ti+3) targets buf read at iter ti-1,
// issued after that iter's gate barrier -> no WAR. vmcnt gate + s_barrier
// publishes cross-wave staging. Tail drains 8 -> 4 -> 0.
// EPI=0: C = acc + bias[n] -> bf16 Cb;  EPI=1: fp32 split-K partials.
// ---------------------------------------------------------------------------
template <int EPI>
__global__ __launch_bounds__(512, 2) void gemm256(
    const ushort* __restrict__ A, const ushort* __restrict__ Bt,
    const float* __restrict__ bias, ushort* __restrict__ Cb,
    float* __restrict__ Out, int M, int N, int K, int KS) {
    __shared__ __align__(16) ushort sA[32768];   // 4 bufs x [4 slots][256][8]
    __shared__ __align__(16) ushort sB[32768];   // 64 KiB each, 128 KiB total
    const int tid  = threadIdx.x;
    const int wave = tid >> 6, lane = tid & 63;
    const int lrow = lane & 15, lquad = lane >> 4;
    const int wm = wave >> 2, wn = wave & 3;

    // B-sharing XCD swizzle: xcd = blk%8 owns n_tiles == blk%8 (mod 8);
    // the 8 m-sharers of each B-panel are 8 apart -> same XCD.
    const int blk = blockIdx.x;
    const int m0 = ((blk >> 3) & 7) * 256;           // M == 2048 assumed
    const int n0 = (((blk >> 6) << 3) + (blk & 7)) * 256;

    const int kb  = (EPI == 1) ? blockIdx.z * KS : 0;
    const int NTl = KS >> 5;                     // K-tiles of 32

    // staging: 16 segments (slot, rowgroup) per matrix; 2 per wave.
    // wave-issue fills 64 consecutive rows of one slot (1 KiB linear LDS).
    const int seg0 = wave * 2, seg1 = seg0 + 1;
    const ushort* aS0 = A  + (size_t)(m0 + (seg0 >> 2)*64 + lane)*K + kb + (seg0 & 3)*8;
    const ushort* aS1 = A  + (size_t)(m0 + (seg1 >> 2)*64 + lane)*K + kb + (seg1 & 3)*8;
    const ushort* bS0 = Bt + (size_t)(n0 + (seg0 >> 2)*64 + lane)*K + kb + (seg0 & 3)*8;
    const ushort* bS1 = Bt + (size_t)(n0 + (seg1 >> 2)*64 + lane)*K + kb + (seg1 & 3)*8;
    ushort* aD0 = sA + (seg0 & 3)*2048 + (seg0 >> 2)*512;
    ushort* aD1 = sA + (seg1 & 3)*2048 + (seg1 >> 2)*512;
    ushort* bD0 = sB + (seg0 & 3)*2048 + (seg0 >> 2)*512;
    ushort* bD1 = sB + (seg1 & 3)*2048 + (seg1 >> 2)*512;

    // fragment read bases: lane l -> row (l&15), k-slot (l>>4)
    const ushort* pA = sA + lquad*2048 + (wm*128 + lrow)*8;
    const ushort* pB = sB + lquad*2048 + (wn*64  + lrow)*8;

    f32x4 acc[8][4];
#pragma unroll
    for (int i = 0; i < 8; ++i)
#pragma unroll
        for (int j = 0; j < 4; ++j) acc[i][j] = f32x4{0.f, 0.f, 0.f, 0.f};

#define STAGE_A(TI) { const int _b = (TI) & 3; const size_t _ko = (size_t)(TI) * 32; \
    g2l16(aS0 + _ko, aD0 + _b*8192); g2l16(aS1 + _ko, aD1 + _b*8192); }
#define STAGE_B(TI) { const int _b = (TI) & 3; const size_t _ko = (size_t)(TI) * 32; \
    g2l16(bS0 + _ko, bD0 + _b*8192); g2l16(bS1 + _ko, bD1 + _b*8192); }

    // prologue: tiles 0,1,2 in flight (12 loads/wave); drain tile 0 -> 8 left
    STAGE_A(0); STAGE_B(0); STAGE_A(1); STAGE_B(1); STAGE_A(2); STAGE_B(2);
    asm volatile("s_waitcnt vmcnt(8)\n\ts_barrier" ::: "memory");

    for (int ti = 0; ti < NTl; ++ti) {
        const ushort* bufA = pA + (ti & 3) * 8192;
        const ushort* bufB = pB + (ti & 3) * 8192;
        const bool st = (ti + 3 < NTl);
        bf16x8 af0[4], af1[4], bg[4];
        // ---------------- phase 1: A-low + B reads || stage A(ti+3) ------
#pragma unroll
        for (int i = 0; i < 4; ++i)
            af0[i] = __builtin_bit_cast(bf16x8, *(const uint4*)(bufA + i*128));
#pragma unroll
        for (int j = 0; j < 4; ++j)
            bg[j] = __builtin_bit_cast(bf16x8, *(const uint4*)(bufB + j*128));
        if (st) STAGE_A(ti + 3);
        asm volatile("s_barrier" ::: "memory");
        asm volatile("s_waitcnt lgkmcnt(0)" ::: "memory");
        __builtin_amdgcn_sched_barrier(0);
        __builtin_amdgcn_s_setprio(1);
#pragma unroll
        for (int i = 0; i < 4; ++i)
#pragma unroll
            for (int j = 0; j < 4; ++j)
                acc[i][j] = __builtin_amdgcn_mfma_f32_16x16x32_bf16(
                    af0[i], bg[j], acc[i][j], 0, 0, 0);
        __builtin_amdgcn_s_setprio(0);
        asm volatile("s_barrier" ::: "memory");
        // ---------------- phase 2: A-high reads || stage B(ti+3) ---------
#pragma unroll
        for (int i = 0; i < 4; ++i)
            af1[i] = __builtin_bit_cast(bf16x8, *(const uint4*)(bufA + (4+i)*128));
        if (st) STAGE_B(ti + 3);
        asm volatile("s_barrier" ::: "memory");
        asm volatile("s_waitcnt lgkmcnt(0)" ::: "memory");
        __builtin_amdgcn_sched_barrier(0);
        __builtin_amdgcn_s_setprio(1);
#pragma unroll
        for (int i = 0; i < 4; ++i)
#pragma unroll
            for (int j = 0; j < 4; ++j)
                acc[4+i][j] = __builtin_amdgcn_mfma_f32_16x16x32_bf16(
                    af1[i], bg[j], acc[4+i][j], 0, 0, 0);
        __builtin_amdgcn_s_setprio(0);
        // ------------- per-K-tile gate: counted vmcnt, never 0 mid-loop --
        if (ti + 3 < NTl)      asm volatile("s_waitcnt vmcnt(8)\n\ts_barrier" ::: "memory");
        else if (ti + 2 < NTl) asm volatile("s_waitcnt vmcnt(4)\n\ts_barrier" ::: "memory");
        else if (ti + 1 < NTl) asm volatile("s_waitcnt vmcnt(0)\n\ts_barrier" ::: "memory");
        // ti == NTl-1: nothing outstanding; epilogue has its own sync
    }
#undef STAGE_A
#undef STAGE_B

    if constexpr (EPI == 0) {
        float bvj[4];
#pragma unroll
        for (int j = 0; j < 4; ++j) bvj[j] = bias[n0 + wn*64 + j*16 + lrow];
        __syncthreads();                    // all waves done with sA/sB
        ushort* warena = sA + wave * 2048;  // 4 KB per wave: 32 rows x 64 cols
#pragma unroll
        for (int pass = 0; pass < 4; ++pass) {
#pragma unroll
            for (int ih = 0; ih < 2; ++ih) {
                const int i = pass*2 + ih;
#pragma unroll
                for (int j = 0; j < 4; ++j)
#pragma unroll
                    for (int re = 0; re < 4; ++re) {
                        int mrow = ih*16 + lquad*4 + re;     // 0..31
                        int col  = j*16 + lrow;              // 0..63
                        warena[mrow*64 + col] = f2b(acc[i][j][re] + bvj[j]);
                    }
            }
            // intra-wave only (lockstep) -> no barrier needed
#pragma unroll
            for (int t2 = 0; t2 < 4; ++t2) {
                int chunk = t2*64 + lane;          // 0..255
                int row = chunk >> 3, seg = chunk & 7;
                uint4 v = *(const uint4*)&warena[row*64 + seg*8];
                *(uint4*)&Cb[(size_t)(m0 + wm*128 + pass*32 + row)*N
                             + n0 + wn*64 + seg*8] = v;
            }
        }
    } else {
        float* P = Out + (size_t)blockIdx.z * M * N;
#pragma unroll
        for (int j = 0; j < 4; ++j) {
            int n = n0 + wn*64 + j*16 + lrow;
#pragma unroll
            for (int i = 0; i < 8; ++i) {
                int mbase = m0 + wm*128 + i*16 + lquad*4;
#pragma unroll
                for (int re = 0; re < 4; ++re)
                    P[(size_t)(mbase + re)*N + n] = acc[i][j][re];
            }
        }
    }
}

// ---------------------------------------------------------------------------
// Per-patch: 8x8 circular conv (q ⊛ k), LN2 over c, gate by v, pack A2 rows.
// One block per patch; thread t -> (head = t>>5, c = t&31). A2 aliases Qb
// (each row fully consumed into regs before overwrite).
// ---------------------------------------------------------------------------
__global__ __launch_bounds__(256, 3) void conv_gate(
    const ushort* __restrict__ Qb, const ushort* __restrict__ Kb,
    const ushort* __restrict__ Vb, const float* __restrict__ ln2_s,
    const float* __restrict__ ln2_b, ushort* __restrict__ A2) {
    __shared__ ushort sT[64 * 258];                // 33 KB, [p or a][h*32+c]
    const int t = threadIdx.x;
    const int m = blockIdx.x;
    const int c = t & 31, h = t >> 5;
    const ushort* Qrow = Qb + (size_t)m * 16384;
    const ushort* Krow = Kb + (size_t)m * 16384;
    const ushort* Vrow = Vb + (size_t)m * 16384;

    // stage transposed: global f = cc*512 + p*8 + head  ->  sT[p*258+head*32+cc]
#define STAGE_T(SRC)                                                        \
    {                                                                       \
        _Pragma("unroll")                                                   \
        for (int it = 0; it < 8; ++it) {                                    \
            int ci = it*256 + t;                                            \
            int p = ci & 63, cc = ci >> 6;                                  \
            uint4 w = ((const uint4*)(SRC))[ci];                            \
            uint uu[4] = {w.x, w.y, w.z, w.w};                              \
            _Pragma("unroll")                                               \
            for (int e = 0; e < 4; ++e) {                                   \
                sT[p*258 + (2*e  )*32 + cc] = (ushort)(uu[e] & 0xffffu);    \
                sT[p*258 + (2*e+1)*32 + cc] = (ushort)(uu[e] >> 16);        \
            }                                                               \
        }                                                                   \
    }

    float q[64];
    STAGE_T(Qrow);
    __syncthreads();
#pragma unroll
    for (int p = 0; p < 64; ++p) q[p] = b2f(sT[p*258 + t]);
    __syncthreads();
    STAGE_T(Krow);     // K stays in LDS for the conv loop
    __syncthreads();
#undef STAGE_T

    const float scl = ln2_s[c], bia = ln2_b[c];
    ushort* A2row = A2 + (size_t)m * 16384;
    const ushort* vbase = Vrow + c*512 + h;        // + p0*64 + p1*8

#pragma unroll
    for (int p0 = 0; p0 < 8; ++p0) {
        // prefetch V octet (consumed after the FMA nest -> latency hidden)
        ushort vraw[8];
#pragma unroll
        for (int p1 = 0; p1 < 8; ++p1) vraw[p1] = vbase[p0*64 + p1*8];

        float o[8];
#pragma unroll
        for (int p1 = 0; p1 < 8; ++p1) o[p1] = 0.f;
#pragma unroll
        for (int b0 = 0; b0 < 8; ++b0) {
            const int qr = ((p0 - b0) & 7) * 8;
#pragma unroll
            for (int b1 = 0; b1 < 8; ++b1) {
                float kv = b2f(sT[(b0*8 + b1)*258 + t]);
#pragma unroll
                for (int p1 = 0; p1 < 8; ++p1)
                    o[p1] += kv * q[qr + ((p1 - b1) & 7)];
            }
        }

        // batched LN2 butterfly over the 32 channels (lanes grouped by 32)
        float s1[8], s2[8];
#pragma unroll
        for (int p1 = 0; p1 < 8; ++p1) { s1[p1] = o[p1]; s2[p1] = o[p1]*o[p1]; }
#pragma unroll
        for (int mask = 1; mask <= 16; mask <<= 1) {
#pragma unroll
            for (int p1 = 0; p1 < 8; ++p1) {
                s1[p1] += __shfl_xor(s1[p1], mask, 64);
                s2[p1] += __shfl_xor(s2[p1], mask, 64);
            }
        }
#pragma unroll
        for (int p1 = 0; p1 < 8; ++p1) {
            float mu  = s1[p1] * 0.03125f;
            float var = s2[p1] * 0.03125f - mu * mu;
            float inv = rsqrtf(var + 1e-6f);
            float on  = (o[p1] - mu) * inv * scl + bia;
            A2row[(p0*8 + p1)*256 + t] = f2b(b2f(vraw[p1]) * on);
        }
    }
}

// ---------------------------------------------------------------------------
// reduce_out: out[pix] = x[pix] + bo[n] + sum_z P[z][m][n], patch->pixel remap
// ---------------------------------------------------------------------------
__global__ __launch_bounds__(256) void reduce_out(
    const float* __restrict__ Pp, const float* __restrict__ x,
    const float* __restrict__ bo, float* __restrict__ out) {
    __shared__ float sn[32*65];                    // padded [c][64]
    const int t = threadIdx.x, m = blockIdx.x;
    float4 s0 = {0.f,0.f,0.f,0.f}, s1 = {0.f,0.f,0.f,0.f};
#pragma unroll
    for (int z = 0; z < 4; ++z) {
        const float4* base =
            (const float4*)(Pp + ((size_t)z*2048 + m) * 2048);
        float4 u = base[t], v = base[256 + t];
        s0.x += u.x; s0.y += u.y; s0.z += u.z; s0.w += u.w;
        s1.x += v.x; s1.y += v.y; s1.z += v.z; s1.w += v.w;
    }
    {
        int na = t*4;                              // chunk t   -> n = 4t
        int nb = (256 + t)*4;                      // chunk 256+t
        float va[4] = {s0.x, s0.y, s0.z, s0.w};
        float vb[4] = {s1.x, s1.y, s1.z, s1.w};
#pragma unroll
        for (int e = 0; e < 4; ++e) {
            int n1 = na + e, n2 = nb + e;
            sn[(n1 >> 6)*65 + (n1 & 63)] = va[e];
            sn[(n2 >> 6)*65 + (n2 & 63)] = vb[e];
        }
    }
    __syncthreads();
    const int c = t & 31, pi = t >> 5;
    const int bb = m >> 10, gh = (m >> 5) & 31, gw = m & 31;
#pragma unroll
    for (int it = 0; it < 8; ++it) {
        int p = it*8 + pi;                         // 0..63
        int p0 = p >> 3, p1 = p & 7;
        int n = c*64 + p;
        size_t oi = ((size_t)((bb*256 + gh*8 + p0)*256 + gw*8 + p1))*32 + c;
        out[oi] = x[oi] + bo[n] + sn[c*65 + p];
    }
}

// ---------------------------------------------------------------------------
extern "C" void kernel_launch(void* const* d_in, const int* in_sizes, int n_in,
                              void* d_out, int out_size, void* d_ws, size_t ws_size,
                              hipStream_t stream) {
    (void)in_sizes; (void)n_in; (void)out_size; (void)ws_size;
    const float* x    = (const float*)d_in[0];
    const float* ln1s = (const float*)d_in[1];
    const float* ln1b = (const float*)d_in[2];
    const float* Wq   = (const float*)d_in[3];
    const float* bq   = (const float*)d_in[4];
    const float* Wk   = (const float*)d_in[5];
    const float* bk   = (const float*)d_in[6];
    const float* Wv   = (const float*)d_in[7];
    const float* bv   = (const float*)d_in[8];
    const float* ln2s = (const float*)d_in[9];
    const float* ln2b = (const float*)d_in[10];
    const float* Wo   = (const float*)d_in[11];
    const float* bo   = (const float*)d_in[12];
    float* out = (float*)d_out;

    char* ws = (char*)d_ws;
    ushort* A1 = (ushort*)(ws);                      //  8.0 MB  [2048,2048] bf16
    ushort* WT = (ushort*)(ws + 8388608);            // 64.0 MB  [N,K] bf16
    ushort* Qb = (ushort*)(ws + 75497472);           // 64.0 MB  [2048,16384] bf16
    ushort* Kb = (ushort*)(ws + 142606336);          // 64.0 MB
    ushort* Vb = (ushort*)(ws + 209715200);          // 64.0 MB  (end 276.8 MB)
    ushort* A2 = Qb;                                 // aliases Qb (safe: per-row)
    float*  Pp = (float*)Kb;                         // 64.0 MB split-K partials
                                                     // (Kb dead after conv_gate)

    ln1_pack<<<512, 256, 0, stream>>>(x, ln1s, ln1b, A1);

    wcvt<<<dim3(256, 32), 256, 0, stream>>>(Wq, WT, 2048, 16384);
    gemm256<0><<<dim3(512, 1, 1), 512, 0, stream>>>(A1, WT, bq, Qb, nullptr,
                                                    2048, 16384, 2048, 2048);
    wcvt<<<dim3(256, 32), 256, 0, stream>>>(Wk, WT, 2048, 16384);
    gemm256<0><<<dim3(512, 1, 1), 512, 0, stream>>>(A1, WT, bk, Kb, nullptr,
                                                    2048, 16384, 2048, 2048);
    wcvt<<<dim3(256, 32), 256, 0, stream>>>(Wv, WT, 2048, 16384);
    gemm256<0><<<dim3(512, 1, 1), 512, 0, stream>>>(A1, WT, bv, Vb, nullptr,
                                                    2048, 16384, 2048, 2048);

    conv_gate<<<2048, 256, 0, stream>>>(Qb, Kb, Vb, ln2s, ln2b, A2);

    wcvt<<<dim3(32, 256), 256, 0, stream>>>(Wo, WT, 16384, 2048);
    gemm256<1><<<dim3(64, 1, 4), 512, 0, stream>>>(A2, WT, nullptr, nullptr, Pp,
                                                   2048, 2048, 16384, 4096);
    reduce_out<<<2048, 256, 0, stream>>>(Pp, x, bo, out);
}